// Round 21
// baseline (95.643 us; speedup 1.0000x reference)
//
#include <hip/hip_runtime.h>

// ActorGCN collapsed-linear, dst-bucketed tile pipeline v6, 8 dispatches.
// Identity: A(xW) = (Ax)W; BN stats of h = yW+b reduce to the 20x20
// covariance of y = A x. Hidden [N,1024] never materialized.
//
// Round 21: r20 (SROWS 256->128) confirmed k_tile is TLP-limited on its
// random x-gather: 108 -> 94.9us total, k_tile out of top-5. Same knob
// again: SROWS 128->64 -> NB=3253 blocks (~12.7/CU queued, 5KB LDS),
// per-block work halves. Scan generalized to NB<=4096 (4 elems/thread);
// dlow = 6 bits in the packed record; stats rotation 8->16 copies
// (contention ~203/word, same as r20); k_counts at 64 threads.
//
// Workspace (floats): deg N | y 20N | stats 16*256 | params 64, then (ints)
// counts NB | bstart NB+1 | cursor NB*32 | erec8 2*E (uint2).
// Total ~20MB; ws is ~268MB (poison fill size) -> ample.

#define F 20
#define NSTAT 230
#define SROWS 64
#define BSZ 256
#define TBSZ 256
#define CPAD 32   // cursor padding stride (ints) = 128B line
#define NCOPY 16  // rotating stats copies

__global__ void k_init(float* __restrict__ deg, float* __restrict__ stats, int N) {
  int i = blockIdx.x * blockDim.x + threadIdx.x;
  if (i < N) deg[i] = 0.f;  // self-loop added at use: deg_true = deg + 1
  if (i < NCOPY * 256) stats[i] = 0.f;
}

// plain degree histogram: atomics spread over 832KB -> no hot lines.
__global__ void k_deg_acc(const int* __restrict__ dst, float* __restrict__ deg, int E) {
  int e = blockIdx.x * blockDim.x + threadIdx.x;
  if (e < E) atomicAdd(&deg[dst[e]], 1.0f);
}

// counts[b] = sum of deg over rows [b*64, b*64+64) — no atomics.
__global__ __launch_bounds__(64) void k_counts(const float* __restrict__ deg,
                                               int* __restrict__ counts, int N) {
  __shared__ float s[64];
  int t = threadIdx.x;
  long row = (long)blockIdx.x * SROWS + t;
  s[t] = (row < N) ? deg[row] : 0.f;
  __syncthreads();
  for (int off = 32; off; off >>= 1) {
    if (t < off) s[t] += s[t + off];
    __syncthreads();
  }
  if (t == 0) counts[blockIdx.x] = (int)(s[0] + 0.5f);
}

// exclusive scan of NB (<=4096) bucket counts, 4 elements/thread
// Hillis-Steele over the 1024 per-thread sums; writes bstart + padded cursor.
__global__ __launch_bounds__(1024) void k_scan(const int* __restrict__ counts,
                                               int* __restrict__ bstart,
                                               int* __restrict__ cursor,
                                               int NB, int E) {
  __shared__ int s[1024];
  int t = threadIdx.x;
  int c[4];
  int i0 = 4 * t;
  #pragma unroll
  for (int u = 0; u < 4; ++u) {
    int i = i0 + u;
    c[u] = (i < NB) ? counts[i] : 0;
  }
  int sum = c[0] + c[1] + c[2] + c[3];
  s[t] = sum;
  __syncthreads();
  for (int off = 1; off < 1024; off <<= 1) {
    int v = (t >= off) ? s[t - off] : 0;
    __syncthreads();
    s[t] += v;
    __syncthreads();
  }
  int base = s[t] - sum;  // exclusive prefix of this thread's 4-group
  #pragma unroll
  for (int u = 0; u < 4; ++u) {
    int i = i0 + u;
    if (i < NB) {
      bstart[i] = base;
      cursor[i * CPAD] = base;
    }
    base += c[u];
  }
  if (t == 0) bstart[NB] = E;
}

// bucket fill, payload inline, packed uint2 record (src | dlow<<22, ns bits).
__global__ void k_fill(const int* __restrict__ src, const int* __restrict__ dst,
                       const float* __restrict__ deg, int* __restrict__ cursor,
                       uint2* __restrict__ erec8, int E) {
  int e = blockIdx.x * blockDim.x + threadIdx.x;
  if (e >= E) return;
  int s = src[e];
  int d = dst[e];
  int pos = atomicAdd(&cursor[(d >> 6) * CPAD], 1);
  uint2 r;
  r.x = (unsigned int)s | ((unsigned int)(d & 63) << 22);
  r.y = __float_as_uint(rsqrtf(deg[s] + 1.0f));
  erec8[pos] = r;
}

// Block b owns dst rows [b*64, b*64+64): accumulate bucket edges into an
// LDS tile via LDS atomics, add self-term, write y once, stats from LDS.
__global__ __launch_bounds__(TBSZ) void k_tile(
    const uint2* __restrict__ erec8, const int* __restrict__ bstart,
    const float* __restrict__ deg,
    const float* __restrict__ state, const float* __restrict__ edge_attr,
    float* __restrict__ y, float* __restrict__ stats, int N, int Ns) {
  __shared__ float tile[SROWS * F];  // 5 KB
  int t = threadIdx.x;

  for (int i4 = t; i4 < SROWS * 5; i4 += TBSZ)
    *reinterpret_cast<float4*>(tile + i4 * 4) = make_float4(0.f, 0.f, 0.f, 0.f);
  __syncthreads();

  // ---- edge accumulation: tile[dlow][f] += ns * x[s][f] ----
  int start = bstart[blockIdx.x];
  int cnt = bstart[blockIdx.x + 1] - start;
  int sb = Ns * F;
  int nit = cnt * F;
  for (int it = t; it < nit; it += TBSZ) {
    int le = it / F;
    int f = it - le * F;
    uint2 r = erec8[start + le];  // sequential 8B load
    int s = r.x & 0x3FFFFF;
    int dlow = r.x >> 22;
    float ns = __uint_as_float(r.y);
    int xi = s * F + f;
    float x = (xi < sb) ? state[xi] : edge_attr[xi - sb];  // THE gather
    atomicAdd(&tile[dlow * F + f], ns * x);
  }
  __syncthreads();

  // ---- self-term: y_full = dinv*(z + dinv*x); single streaming writeback ----
  long rowbase = (long)blockIdx.x * SROWS;
  for (int i4 = t; i4 < SROWS * 5; i4 += TBSZ) {
    int rl = i4 / 5;
    int q = i4 - rl * 5;
    long row = rowbase + rl;
    float4 v = make_float4(0.f, 0.f, 0.f, 0.f);
    if (row < N) {
      float4 zv = *reinterpret_cast<const float4*>(tile + i4 * 4);
      const float* xrow = (row < (long)Ns) ? (state + row * F)
                                           : (edge_attr + (row - Ns) * F);
      float4 xv = *reinterpret_cast<const float4*>(xrow + q * 4);
      float di = rsqrtf(deg[row] + 1.0f);
      v.x = di * (zv.x + di * xv.x);
      v.y = di * (zv.y + di * xv.y);
      v.z = di * (zv.z + di * xv.z);
      v.w = di * (zv.w + di * xv.w);
      *reinterpret_cast<float4*>(y + row * F + q * 4) = v;  // for k_out
    }
    *reinterpret_cast<float4*>(tile + i4 * 4) = v;
  }
  __syncthreads();

  // ---- stats from LDS tile (64 rows); 16 rotating copies cut contention ----
  float* st = stats + (blockIdx.x & (NCOPY - 1)) * 256;
  if (t < F) {
    float a0 = 0.f, a1 = 0.f, a2 = 0.f, a3 = 0.f;
    for (int r = 0; r < SROWS; r += 4) {
      a0 += tile[(r + 0) * F + t];
      a1 += tile[(r + 1) * F + t];
      a2 += tile[(r + 2) * F + t];
      a3 += tile[(r + 3) * F + t];
    }
    atomicAdd(&st[t], (a0 + a1) + (a2 + a3));
  } else if (t < NSTAT) {
    int k = t - F, i = 0;
    while (k >= F - i) { k -= F - i; i++; }
    int ci = i, cj = i + k;
    float a0 = 0.f, a1 = 0.f, a2 = 0.f, a3 = 0.f;
    for (int r = 0; r < SROWS; r += 4) {
      a0 += tile[(r + 0) * F + ci] * tile[(r + 0) * F + cj];
      a1 += tile[(r + 1) * F + ci] * tile[(r + 1) * F + cj];
      a2 += tile[(r + 2) * F + ci] * tile[(r + 2) * F + cj];
      a3 += tile[(r + 3) * F + ci] * tile[(r + 3) * F + cj];
    }
    atomicAdd(&st[t], (a0 + a1) + (a2 + a3));
  }
}

// Single block, 256 threads, launch_bounds(256,1): 4 waves -> up to 512
// VGPR/thread; w[4][20] + m0[20] + m1[20] live in registers (round-4 proven).
// Sums the 16 stats copies on load.
__global__ __launch_bounds__(256, 1) void k_finalize(
    const float* __restrict__ stats,
    const float* __restrict__ W_gcn,
    const float* __restrict__ gamma,
    const float* __restrict__ beta,
    const float* __restrict__ W_lin,
    const float* __restrict__ b_lin,
    float* __restrict__ params,
    int N, int H) {
  __shared__ float Cu_s[210];
  __shared__ float ybar_s[F];
  __shared__ float part[4][44];
  int t = threadIdx.x;
  int lane = t & 63;
  int wv = t >> 6;
  float invN = 1.0f / (float)N;
  if (t < F) {
    float s = 0.f;
    for (int k = 0; k < NCOPY; ++k) s += stats[k * 256 + t];
    ybar_s[t] = s * invN;
  }
  __syncthreads();
  if (t < 210) {
    int k = t, i = 0;
    while (k >= F - i) { k -= F - i; i++; }
    int j = i + k;
    float sv = 0.f;
    for (int c = 0; c < NCOPY; ++c) sv += stats[c * 256 + F + t];
    float cv = sv * invN - ybar_s[i] * ybar_s[j];
    Cu_s[t] = (i == j) ? cv : 2.0f * cv;  // fold symmetry factor
  }
  __syncthreads();

  float m0[F], m1[F];
  #pragma unroll
  for (int f = 0; f < F; ++f) { m0[f] = 0.f; m1[f] = 0.f; }
  float d0 = 0.f, d1 = 0.f;

  for (int hb = 0; hb < H; hb += 4 * 256) {
    float w[4][F];
    float var[4];
    int hh[4];
    bool act[4];
    #pragma unroll
    for (int c = 0; c < 4; ++c) {
      int h = hb + c * 256 + t;
      act[c] = (h < H);
      hh[c] = act[c] ? h : 0;
      var[c] = 0.f;
      #pragma unroll
      for (int f = 0; f < F; ++f) {
        float x = W_gcn[f * H + hh[c]];  // coalesced over t
        w[c][f] = act[c] ? x : 0.f;
      }
    }
    int p = 0;
    #pragma unroll
    for (int i = 0; i < F; ++i) {
      #pragma unroll
      for (int j = i; j < F; ++j) {
        float cu = Cu_s[p];  // uniform broadcast, reused 4x
        ++p;
        #pragma unroll
        for (int c = 0; c < 4; ++c) var[c] += cu * (w[c][i] * w[c][j]);
      }
    }
    #pragma unroll
    for (int c = 0; c < 4; ++c) {
      float sg = act[c] ? (gamma[hh[c]] * rsqrtf(var[c] + 1e-5f)) : 0.f;
      float wl0 = W_lin[hh[c] * 2 + 0], wl1 = W_lin[hh[c] * 2 + 1];
      float s0 = sg * wl0, s1 = sg * wl1;
      #pragma unroll
      for (int f = 0; f < F; ++f) { m0[f] += w[c][f] * s0; m1[f] += w[c][f] * s1; }
      float bt = act[c] ? beta[hh[c]] : 0.f;
      d0 += bt * wl0;
      d1 += bt * wl1;
    }
  }

  #pragma unroll
  for (int f = 0; f < F; ++f) {
    float v0 = m0[f], v1 = m1[f];
    #pragma unroll
    for (int off = 32; off; off >>= 1) {
      v0 += __shfl_xor(v0, off);
      v1 += __shfl_xor(v1, off);
    }
    if (lane == 0) { part[wv][2 * f] = v0; part[wv][2 * f + 1] = v1; }
  }
  #pragma unroll
  for (int off = 32; off; off >>= 1) {
    d0 += __shfl_xor(d0, off);
    d1 += __shfl_xor(d1, off);
  }
  if (lane == 0) { part[wv][40] = d0; part[wv][41] = d1; }
  __syncthreads();

  if (t < 42) {
    float acc = 0.f;
    for (int w2 = 0; w2 < 4; ++w2) acc += part[w2][t];
    if (t >= 40) acc += b_lin[t - 40];
    params[t] = acc;
  } else if (t < 62) {
    params[t] = ybar_s[t - 42];
  }
}

// thread per node: logits = (y[n]-ybar) @ M + d; relu; 2-way softmax.
__global__ void k_out(const float* __restrict__ y,
                      const float* __restrict__ params,
                      float* __restrict__ out, int N) {
  __shared__ float P[64];
  if (threadIdx.x < 62) P[threadIdx.x] = params[threadIdx.x];
  __syncthreads();
  int n = blockIdx.x * blockDim.x + threadIdx.x;
  if (n >= N) return;
  const float4* yr4 = reinterpret_cast<const float4*>(y + (size_t)n * F);
  float l0 = P[40], l1 = P[41];
  #pragma unroll
  for (int k = 0; k < 5; ++k) {
    float4 q = yr4[k];
    float vv[4] = {q.x, q.y, q.z, q.w};
    #pragma unroll
    for (int u = 0; u < 4; ++u) {
      int f = 4 * k + u;
      float dv = vv[u] - P[42 + f];
      l0 += dv * P[2 * f + 0];
      l1 += dv * P[2 * f + 1];
    }
  }
  l0 = fmaxf(l0, 0.f);
  l1 = fmaxf(l1, 0.f);
  float m = fmaxf(l0, l1);
  float e0 = __expf(l0 - m), e1 = __expf(l1 - m);
  float inv = 1.0f / (e0 + e1);
  float2 o2;
  o2.x = e0 * inv;
  o2.y = e1 * inv;
  reinterpret_cast<float2*>(out)[n] = o2;
}

extern "C" void kernel_launch(void* const* d_in, const int* in_sizes, int n_in,
                              void* d_out, int out_size, void* d_ws, size_t ws_size,
                              hipStream_t stream) {
  const float* state     = (const float*)d_in[0];
  const float* edge_attr = (const float*)d_in[1];
  const int*   eidx      = (const int*)d_in[2];
  const float* W_gcn     = (const float*)d_in[3];
  // d_in[4] = b_gcn: cancels inside batchnorm, unused.
  const float* gamma     = (const float*)d_in[5];
  const float* beta      = (const float*)d_in[6];
  const float* W_lin     = (const float*)d_in[7];
  const float* b_lin     = (const float*)d_in[8];
  float* out = (float*)d_out;

  int Ns = in_sizes[0] / F;
  int E  = in_sizes[2] / 2;
  int N  = Ns + in_sizes[1] / F;
  int H  = in_sizes[4];

  const int* src = eidx;
  const int* dst = eidx + E;

  int NB = (N + SROWS - 1) / SROWS;  // 3253 for N=208192 (<=4096 for k_scan)

  float* ws     = (float*)d_ws;
  float* deg    = ws;
  float* y      = ws + N;
  float* stats  = y + (size_t)N * F;      // NCOPY*256 floats
  float* params = stats + NCOPY * 256;
  int*   counts = (int*)(params + 64);
  int*   bstart = counts + NB;
  int*   cursor = bstart + NB + 1;        // NB*CPAD ints, padded
  uint2* erec8  = (uint2*)(cursor + NB * CPAD);

  k_init<<<(N + BSZ - 1) / BSZ, BSZ, 0, stream>>>(deg, stats, N);
  k_deg_acc<<<(E + BSZ - 1) / BSZ, BSZ, 0, stream>>>(dst, deg, E);
  k_counts<<<NB, 64, 0, stream>>>(deg, counts, N);
  k_scan<<<1, 1024, 0, stream>>>(counts, bstart, cursor, NB, E);
  k_fill<<<(E + BSZ - 1) / BSZ, BSZ, 0, stream>>>(src, dst, deg, cursor,
                                                  erec8, E);
  k_tile<<<NB, TBSZ, 0, stream>>>(erec8, bstart, deg, state, edge_attr,
                                  y, stats, N, Ns);
  k_finalize<<<1, 256, 0, stream>>>(stats, W_gcn, gamma, beta, W_lin, b_lin,
                                    params, N, H);
  k_out<<<(N + BSZ - 1) / BSZ, BSZ, 0, stream>>>(y, params, out, N);
}